// Round 2
// baseline (1330.003 us; speedup 1.0000x reference)
//
#include <hip/hip_runtime.h>
#include <math.h>

#define PP 128
#define DD 128
#define RR 16384
#define EE 131072
#define TT 1024
#define FF 513
#define FP 520      /* padded frequency count (multiple of 8) */
#define FP2 1040    /* floats per row of an interleaved complex plane */

#define TAU_SCALE 46.64723032069971    /* SR / C_SOUND */
#define KDECAY   -0.0211392282f        /* LOG_GAMMA/C - AIR */
#define LOG_GAMMA -6.907755278982137f
#define TWO_PI    6.283185307179586

#define FMA4(A, K, V) { A.x = fmaf(K, V.x, A.x); A.y = fmaf(K, V.y, A.y); \
                        A.z = fmaf(K, V.z, A.z); A.w = fmaf(K, V.w, A.w); }

__device__ __forceinline__ void pf_sincos(float tau, int f, float* s, float* c) {
    // phase = exp(-2*pi*i * tau * f / T); reduce in double, eval in float
    double rev = (double)tau * (double)f * (1.0 / 1024.0);
    rev -= floor(rev);
    float ang = (float)(-TWO_PI * rev);
    __sincosf(ang, s, c);
}

// ---- per-row precompute: amp_src, tau_src, amp_rec, tau_rec, dec_prop, tau_prop
__global__ void k_per_row(const float* __restrict__ rpos,
                          const float* __restrict__ spos,
                          const float* __restrict__ cpos,
                          const float* __restrict__ avg_dist,
                          float* __restrict__ per_row) {
    int r = blockIdx.x * blockDim.x + threadIdx.x;
    if (r >= RR) return;
    float x = rpos[3*r], y = rpos[3*r+1], z = rpos[3*r+2];

    float dx = x - spos[0], dy = y - spos[1], dz = z - spos[2];
    float ds = sqrtf(dx*dx + dy*dy + dz*dz);
    per_row[0*RR + r] = (1.0f/(ds*ds + 0.001f)) * expf(KDECAY * ds);
    per_row[1*RR + r] = ds * (float)TAU_SCALE;

    dx = x - cpos[0]; dy = y - cpos[1]; dz = z - cpos[2];
    float dr = sqrtf(dx*dx + dy*dy + dz*dz);
    per_row[2*RR + r] = (1.0f/(dr*dr + 0.001f)) * expf(KDECAY * dr);
    per_row[3*RR + r] = dr * (float)TAU_SCALE;

    float da = avg_dist[r];
    per_row[4*RR + r] = expf(KDECAY * da);
    per_row[5*RR + r] = da * (float)TAU_SCALE;
}

// ---- K[p][d][e] = c0[p]*basis0[d][e] + c1[p]*basis1[d][e]
__global__ void k_build_K(const float* __restrict__ absorption,
                          const float* __restrict__ scattering,
                          const int* __restrict__ object_ids,
                          const float* __restrict__ basis,
                          float* __restrict__ Kmat) {
    int idx = blockIdx.x * 256 + threadIdx.x;   // < P*D*D
    int p  = idx >> 14;
    int de = idx & 16383;
    int obj = object_ids[p];
    float refl = 1.0f - absorption[obj];
    float sc   = scattering[obj];
    Kmat[idx] = refl*sc*basis[de] + refl*(1.0f - sc)*basis[16384 + de];
}

// ---- CSR build
__global__ void k_count(const int* __restrict__ gk_row, int* __restrict__ counts) {
    int e = blockIdx.x * 256 + threadIdx.x;
    atomicAdd(&counts[gk_row[e]], 1);
}

__global__ __launch_bounds__(1024) void k_scan(const int* __restrict__ counts,
                                               int* __restrict__ row_start,
                                               int* __restrict__ cursor) {
    __shared__ int sh[1024];
    int tid = threadIdx.x;
    int base = tid * 16;
    int local[16];
    int sum = 0;
    #pragma unroll
    for (int j = 0; j < 16; j++) { local[j] = sum; sum += counts[base + j]; }
    sh[tid] = sum;
    __syncthreads();
    for (int off = 1; off < 1024; off <<= 1) {
        int v = (tid >= off) ? sh[tid - off] : 0;
        __syncthreads();
        sh[tid] += v;
        __syncthreads();
    }
    int chunk_excl = sh[tid] - sum;   // exclusive prefix of this 16-chunk
    #pragma unroll
    for (int j = 0; j < 16; j++) {
        int v = chunk_excl + local[j];
        row_start[base + j] = v;
        cursor[base + j] = v;
    }
    if (tid == 1023) row_start[RR] = chunk_excl + sum;
}

// scatter with pre-gathered val/col (kills double indirection in segsum)
__global__ void k_scatter(const int* __restrict__ gk_row,
                          const float* __restrict__ gk_val,
                          const int* __restrict__ gk_col,
                          int* __restrict__ cursor,
                          float* __restrict__ val_s, int* __restrict__ col_s) {
    int e = blockIdx.x * 256 + threadIdx.x;
    int pos = atomicAdd(&cursor[gk_row[e]], 1);
    val_s[pos] = gk_val[e];
    col_s[pos] = gk_col[e];
}

// ---- init: cur[row,f] = amp_src*phase(tau_src); fused echo contribution of rad
__global__ __launch_bounds__(256) void k_init(const float* __restrict__ per_row,
                                              float* __restrict__ cur_cc,
                                              float* __restrict__ echo_part) {
    __shared__ float2 sh[8][33];
    int fl = threadIdx.x & 31, ry = threadIdx.x >> 5;
    int row = (blockIdx.x << 3) + ry;
    float amp = per_row[row],      tau  = per_row[RR + row];
    float w   = per_row[2*RR+row], taur = per_row[3*RR + row];
    for (int it = 0; it < 17; it++) {
        int fo = (it << 5) + fl;
        float re = 0.f, im = 0.f;
        float2 contrib = make_float2(0.f, 0.f);
        if (fo < FP) {
            float s, c; pf_sincos(tau, fo, &s, &c);
            re = amp * c; im = amp * s;
            *(float2*)(cur_cc + (size_t)row * FP2 + fo * 2) = make_float2(re, im);
            if (fo < FF) {
                float s2, c2; pf_sincos(taur, fo, &s2, &c2);
                contrib.x = w * (c2*re - s2*im);
                contrib.y = w * (c2*im + s2*re);
            }
        }
        sh[ry][fl] = contrib;
        __syncthreads();
        if (ry == 0 && fo < FF) {
            float sx = 0.f, sy = 0.f;
            #pragma unroll
            for (int r = 0; r < 8; r++) { sx += sh[r][fl].x; sy += sh[r][fl].y; }
            float* ep = echo_part + (size_t)(blockIdx.x & 31) * FP2;
            atomicAdd(&ep[2*fo],     sx);
            atomicAdd(&ep[2*fo + 1], sy);
        }
        __syncthreads();
    }
}

// ---- matmul + prop: out[p,d,f] = prop(row,f) * sum_e K[p,d,e]*in[p,e,f]
// blockIdx.x < 8: (ftile = x>>2 covers 256 f, dtile = x&3 covers 32 d), y = p.
// blockIdx.x == 8: tail block, f in {512..519}, all 128 d.
__global__ __launch_bounds__(256) void k_matmul(const float* __restrict__ Kmat,
                                                const float* __restrict__ in_cc,
                                                const float* __restrict__ per_row,
                                                float* __restrict__ out_cc) {
    __shared__ float Klds[128 * 36];
    int p = blockIdx.y;
    int tid = threadIdx.x;
    if (blockIdx.x < 8) {
        int ftile = blockIdx.x >> 2;
        int dblk  = (blockIdx.x & 3) << 5;
        const float* Kp = Kmat + p * 16384 + dblk * 128;
        for (int i = tid; i < 4096; i += 256) {
            Klds[(i & 127) * 36 + (i >> 7)] = Kp[i];
        }
        __syncthreads();
        int fl = tid & 63, dg = tid >> 6;
        int f = (ftile << 8) + (fl << 2);        // <= 508, always in range
        const float* base = in_cc + (size_t)(p << 7) * FP2 + f * 2;
        float4 accA[8], accB[8];
        #pragma unroll
        for (int j = 0; j < 8; j++) {
            accA[j] = make_float4(0.f,0.f,0.f,0.f);
            accB[j] = make_float4(0.f,0.f,0.f,0.f);
        }
        for (int e = 0; e < 128; e++) {
            const float4* v = (const float4*)(base + (size_t)e * FP2);
            float4 v01 = v[0], v23 = v[1];
            const float4* kp4 = (const float4*)&Klds[e * 36 + (dg << 3)];
            float4 k0 = kp4[0], k1 = kp4[1];
            FMA4(accA[0], k0.x, v01); FMA4(accB[0], k0.x, v23);
            FMA4(accA[1], k0.y, v01); FMA4(accB[1], k0.y, v23);
            FMA4(accA[2], k0.z, v01); FMA4(accB[2], k0.z, v23);
            FMA4(accA[3], k0.w, v01); FMA4(accB[3], k0.w, v23);
            FMA4(accA[4], k1.x, v01); FMA4(accB[4], k1.x, v23);
            FMA4(accA[5], k1.y, v01); FMA4(accB[5], k1.y, v23);
            FMA4(accA[6], k1.z, v01); FMA4(accB[6], k1.z, v23);
            FMA4(accA[7], k1.w, v01); FMA4(accB[7], k1.w, v23);
        }
        int d0 = dblk + (dg << 3);
        #pragma unroll
        for (int j = 0; j < 8; j++) {
            int row = (p << 7) + d0 + j;
            float dec = per_row[4*RR + row];
            float tau = per_row[5*RR + row];
            float4 a = accA[j], b = accB[j];
            float s0,c0,s1,c1,s2,c2,s3,c3;
            pf_sincos(tau, f,   &s0, &c0);
            pf_sincos(tau, f+1, &s1, &c1);
            pf_sincos(tau, f+2, &s2, &c2);
            pf_sincos(tau, f+3, &s3, &c3);
            float4 o01, o23;
            o01.x = dec*(a.x*c0 - a.y*s0); o01.y = dec*(a.y*c0 + a.x*s0);
            o01.z = dec*(a.z*c1 - a.w*s1); o01.w = dec*(a.w*c1 + a.z*s1);
            o23.x = dec*(b.x*c2 - b.y*s2); o23.y = dec*(b.y*c2 + b.x*s2);
            o23.z = dec*(b.z*c3 - b.w*s3); o23.w = dec*(b.w*c3 + b.z*s3);
            float4* o = (float4*)(out_cc + (size_t)row * FP2 + f * 2);
            o[0] = o01; o[1] = o23;
        }
    } else {
        // tail: 8 frequencies (512..519), all d; K streamed from L2
        int d = tid & 127;
        int f = 512 + ((tid >> 7) << 2);
        const float* Kp = Kmat + p * 16384 + d * 128;
        const float* base = in_cc + (size_t)(p << 7) * FP2 + f * 2;
        float4 aA = make_float4(0.f,0.f,0.f,0.f), aB = make_float4(0.f,0.f,0.f,0.f);
        for (int e = 0; e < 128; e++) {
            float k = Kp[e];
            const float4* v = (const float4*)(base + (size_t)e * FP2);
            float4 v01 = v[0], v23 = v[1];
            FMA4(aA, k, v01); FMA4(aB, k, v23);
        }
        int row = (p << 7) + d;
        float dec = per_row[4*RR + row];
        float tau = per_row[5*RR + row];
        float s0,c0,s1,c1,s2,c2,s3,c3;
        pf_sincos(tau, f,   &s0, &c0);
        pf_sincos(tau, f+1, &s1, &c1);
        pf_sincos(tau, f+2, &s2, &c2);
        pf_sincos(tau, f+3, &s3, &c3);
        float4 o01, o23;
        o01.x = dec*(aA.x*c0 - aA.y*s0); o01.y = dec*(aA.y*c0 + aA.x*s0);
        o01.z = dec*(aA.z*c1 - aA.w*s1); o01.w = dec*(aA.w*c1 + aA.z*s1);
        o23.x = dec*(aB.x*c2 - aB.y*s2); o23.y = dec*(aB.y*c2 + aB.x*s2);
        o23.z = dec*(aB.z*c3 - aB.w*s3); o23.w = dec*(aB.w*c3 + aB.z*s3);
        float4* o = (float4*)(out_cc + (size_t)row * FP2 + f * 2);
        o[0] = o01; o[1] = o23;
    }
}

// ---- segment sum, f-chunked + XCD-partitioned, fused echo epilogue.
// 16 f-chunks of 32 f (chunk 15 covers 40). chunk = (blockIdx&7)*2 + bit -> each
// XCD's L2 only ever holds its own chunk's gather footprint (~4.2 MB).
__global__ __launch_bounds__(256) void k_segsum(const int* __restrict__ row_start,
                                                const float* __restrict__ val_s,
                                                const int* __restrict__ col_s,
                                                const float* __restrict__ in_cc,
                                                float* __restrict__ cur_cc,
                                                const float* __restrict__ per_row,
                                                float* __restrict__ echo_part) {
    __shared__ float2 sh[8][33];
    int b = blockIdx.x;
    int xcd = b & 7, slot = b >> 3;
    int chunk = (xcd << 1) + (slot >> 11);
    int rowblk = slot & 2047;
    int f0 = chunk << 5;
    int fend = (chunk == 15) ? FP : f0 + 32;
    int fl = threadIdx.x & 31, ry = threadIdx.x >> 5;
    int row = (rowblk << 3) + ry;
    int s0 = row_start[row], s1 = row_start[row + 1];
    float w = per_row[2*RR + row], taur = per_row[3*RR + row];
    int nIter = (fend - f0 + 31) >> 5;     // uniform across block
    for (int it = 0; it < nIter; it++) {
        int fo = f0 + (it << 5) + fl;
        bool act = fo < fend;
        float ar = 0.f, ai = 0.f;
        if (act) {
            for (int k = s0; k < s1; k++) {
                float v = val_s[k];
                int c = col_s[k];
                float2 vv = *(const float2*)(in_cc + (size_t)c * FP2 + fo * 2);
                ar = fmaf(v, vv.x, ar);
                ai = fmaf(v, vv.y, ai);
            }
            *(float2*)(cur_cc + (size_t)row * FP2 + fo * 2) = make_float2(ar, ai);
        }
        float2 contrib = make_float2(0.f, 0.f);
        if (act && fo < FF) {
            float s, c; pf_sincos(taur, fo, &s, &c);
            contrib.x = w * (c*ar - s*ai);
            contrib.y = w * (c*ai + s*ar);
        }
        sh[ry][fl] = contrib;
        __syncthreads();
        if (ry == 0 && fo < FF) {
            float sx = 0.f, sy = 0.f;
            #pragma unroll
            for (int r = 0; r < 8; r++) { sx += sh[r][fl].x; sy += sh[r][fl].y; }
            float* ep = echo_part + (size_t)(rowblk & 31) * FP2;
            atomicAdd(&ep[2*fo],     sx);
            atomicAdd(&ep[2*fo + 1], sy);
        }
        __syncthreads();
    }
}

// ---- fold 32 echo partitions
__global__ void k_fold(const float* __restrict__ echo_part, float* __restrict__ echo) {
    int idx = blockIdx.x * 256 + threadIdx.x;
    if (idx < 2 * FF) {
        float s = 0.f;
        for (int p = 0; p < 32; p++) s += echo_part[(size_t)p * FP2 + idx];
        echo[idx] = s;
    }
}

// ---- irfft(n=1024) / fsm_window
__global__ void k_irfft(const float* __restrict__ echo, float* __restrict__ out) {
    int t = blockIdx.x * blockDim.x + threadIdx.x;   // 0..1023
    float acc = echo[0];                              // f=0 (real)
    float nyq = echo[2 * 512];                        // Nyquist real part
    acc += (t & 1) ? -nyq : nyq;
    for (int f = 1; f < 512; f++) {
        int m = (f * t) & 1023;
        float ang = (float)m * 0.006135923151542565f;  // 2*pi/1024
        float s, c; __sincosf(ang, &s, &c);
        acc += 2.0f * (echo[2*f]*c - echo[2*f+1]*s);
    }
    acc *= (1.0f / 1024.0f);
    float tsec = (float)t * (1.0f / 16000.0f);
    float win = expf(LOG_GAMMA * tsec);
    out[t] = acc / win;
}

extern "C" void kernel_launch(void* const* d_in, const int* in_sizes, int n_in,
                              void* d_out, int out_size, void* d_ws, size_t ws_size,
                              hipStream_t stream) {
    const float* source_pos   = (const float*)d_in[0];
    const float* receiver_pos = (const float*)d_in[1];
    const float* absorption   = (const float*)d_in[2];
    const float* scattering   = (const float*)d_in[3];
    const float* gk_val       = (const float*)d_in[4];
    const float* basis        = (const float*)d_in[5];
    const float* avg_dist     = (const float*)d_in[6];
    const float* rpos         = (const float*)d_in[7];
    const int*   gk_row       = (const int*)d_in[8];
    const int*   gk_col       = (const int*)d_in[9];
    const int*   object_ids   = (const int*)d_in[10];
    float* out = (float*)d_out;

    char* base = (char*)d_ws;
    size_t off = 0;
    auto alloc = [&](size_t bytes) -> void* {
        void* ptr = base + off;
        off = (off + bytes + 255) & ~(size_t)255;
        return ptr;
    };
    const size_t PLANE = (size_t)RR * FP2;   // interleaved complex plane
    float* Kmat      = (float*)alloc(sizeof(float) * PP * DD * DD);
    float* cur_cc    = (float*)alloc(sizeof(float) * PLANE);
    float* nxt_cc    = (float*)alloc(sizeof(float) * PLANE);
    float* per_row   = (float*)alloc(sizeof(float) * 6 * RR);
    int*   counts    = (int*)alloc(sizeof(int) * RR);
    int*   row_start = (int*)alloc(sizeof(int) * (RR + 1));
    int*   cursor    = (int*)alloc(sizeof(int) * RR);
    float* val_s     = (float*)alloc(sizeof(float) * EE);
    int*   col_s     = (int*)alloc(sizeof(int) * EE);
    float* echo_part = (float*)alloc(sizeof(float) * 32 * FP2);
    float* echo      = (float*)alloc(sizeof(float) * FP2);

    hipMemsetAsync(counts, 0, sizeof(int) * RR, stream);
    hipMemsetAsync(echo_part, 0, sizeof(float) * 32 * FP2, stream);

    k_per_row<<<RR / 256, 256, 0, stream>>>(rpos, source_pos, receiver_pos, avg_dist, per_row);
    k_build_K<<<(PP * DD * DD) / 256, 256, 0, stream>>>(absorption, scattering, object_ids, basis, Kmat);
    k_count<<<EE / 256, 256, 0, stream>>>(gk_row, counts);
    k_scan<<<1, 1024, 0, stream>>>(counts, row_start, cursor);
    k_scatter<<<EE / 256, 256, 0, stream>>>(gk_row, gk_val, gk_col, cursor, val_s, col_s);
    k_init<<<RR / 8, 256, 0, stream>>>(per_row, cur_cc, echo_part);

    for (int b = 0; b < 4; b++) {
        k_matmul<<<dim3(9, PP), 256, 0, stream>>>(Kmat, cur_cc, per_row, nxt_cc);
        k_segsum<<<32768, 256, 0, stream>>>(row_start, val_s, col_s,
                                            nxt_cc, cur_cc, per_row, echo_part);
    }

    k_fold<<<5, 256, 0, stream>>>(echo_part, echo);
    k_irfft<<<4, 256, 0, stream>>>(echo, out);
}